// Round 1
// baseline (7583.229 us; speedup 1.0000x reference)
//
#include <hip/hip_runtime.h>

#define NN 100000
#define NE 1600000
#define EPS_BN 1e-5f

// ---------------- degree / norm ----------------
__global__ void k_init_deg(float* __restrict__ deg) {
    int i = blockIdx.x * 256 + threadIdx.x;
    if (i < NN) deg[i] = 1.0f;   // self-loop
}

__global__ void k_count(const int* __restrict__ dst, float* __restrict__ deg) {
    int e = blockIdx.x * 256 + threadIdx.x;
    if (e < NE) atomicAdd(&deg[dst[e]], 1.0f);
}

__global__ void k_rsqrt_inplace(float* __restrict__ deg) {
    int i = blockIdx.x * 256 + threadIdx.x;
    if (i < NN) deg[i] = rsqrtf(deg[i]);   // deg -> dinv
}

// ---------------- GEMM: out[N,128] = in[N,128] @ W[128,128] ----------------
__global__ __launch_bounds__(256) void k_gemm128(const float* __restrict__ in,
                                                 const float* __restrict__ W,
                                                 float* __restrict__ out) {
    __shared__ float xs[32][128];
    const int tid = threadIdx.x;
    const int row0 = blockIdx.x * 32;
    // stage 32 input rows (16 KB) into LDS, coalesced float4
    for (int i = tid; i < 32 * 32; i += 256)
        ((float4*)xs)[i] = ((const float4*)(in + (size_t)row0 * 128))[i];
    __syncthreads();

    const int cg = tid & 31;   // column group: cols cg*4 .. cg*4+3
    const int rg = tid >> 5;   // row group:    rows rg*4 .. rg*4+3
    float acc[4][4] = {};
    const float* Wp = W + cg * 4;
    for (int k = 0; k < 128; k += 4) {
        float xr[4][4], wv[4][4];
        #pragma unroll
        for (int i = 0; i < 4; ++i)
            *(float4*)xr[i] = *(const float4*)&xs[rg * 4 + i][k];
        #pragma unroll
        for (int kk = 0; kk < 4; ++kk)
            *(float4*)wv[kk] = *(const float4*)&Wp[(size_t)(k + kk) * 128];
        #pragma unroll
        for (int i = 0; i < 4; ++i)
            #pragma unroll
            for (int kk = 0; kk < 4; ++kk)
                #pragma unroll
                for (int j = 0; j < 4; ++j)
                    acc[i][j] += xr[i][kk] * wv[kk][j];
    }
    #pragma unroll
    for (int i = 0; i < 4; ++i) {
        float4 o = {acc[i][0], acc[i][1], acc[i][2], acc[i][3]};
        *(float4*)&out[(size_t)(row0 + rg * 4 + i) * 128 + cg * 4] = o;
    }
}

// ---------------- GEMM: out[N,40] = in[N,128] @ W[128,40] ----------------
__global__ void k_gemm40(const float* __restrict__ in, const float* __restrict__ W,
                         float* __restrict__ out) {
    int idx = blockIdx.x * 256 + threadIdx.x;
    if (idx >= NN * 40) return;
    int row = idx / 40, col = idx - row * 40;
    const float* xp = in + (size_t)row * 128;
    float acc = 0.f;
    #pragma unroll 8
    for (int k = 0; k < 128; ++k) acc += xp[k] * W[k * 40 + col];
    out[idx] = acc;
}

// ---------------- agg init: self-loop message + bias ----------------
template <int F>
__global__ void k_selfinit(const float* __restrict__ h, const float* __restrict__ dinv,
                           const float* __restrict__ bias, float* __restrict__ agg) {
    int idx = blockIdx.x * 256 + threadIdx.x;
    if (idx >= NN * (F / 4)) return;
    int i = idx / (F / 4);
    int fg = idx - i * (F / 4);
    float d = dinv[i];
    float s = d * d;
    float4 hv = ((const float4*)h)[idx];
    float4 bv = *(const float4*)&bias[fg * 4];
    float4 o;
    o.x = hv.x * s + bv.x;
    o.y = hv.y * s + bv.y;
    o.z = hv.z * s + bv.z;
    o.w = hv.w * s + bv.w;
    ((float4*)agg)[idx] = o;
}

// ---------------- edge scatter with atomics ----------------
template <int F>
__global__ void k_scatter(const int* __restrict__ src, const int* __restrict__ dst,
                          const float* __restrict__ dinv, const float* __restrict__ h,
                          float* __restrict__ agg) {
    const int FG = F / 4;
    long long idx = (long long)blockIdx.x * 256 + threadIdx.x;
    if (idx >= (long long)NE * FG) return;
    int e = (int)(idx / FG);
    int fg = (int)(idx - (long long)e * FG);
    int s = src[e], d = dst[e];
    float nrm = dinv[s] * dinv[d];
    float4 hv = *(const float4*)&h[(size_t)s * F + fg * 4];
    float* ap = &agg[(size_t)d * F + fg * 4];
    atomicAdd(ap + 0, hv.x * nrm);
    atomicAdd(ap + 1, hv.y * nrm);
    atomicAdd(ap + 2, hv.z * nrm);
    atomicAdd(ap + 3, hv.w * nrm);
}

// ---------------- batchnorm ----------------
__global__ void k_zero_stats(float* __restrict__ stats) {
    stats[threadIdx.x] = 0.f;   // 256 entries: [0:128) sum, [128:256) sumsq
}

__global__ __launch_bounds__(256) void k_bnstats(const float* __restrict__ h,
                                                 float* __restrict__ stats) {
    int cg = threadIdx.x & 31;   // column group (4 cols)
    int rl = threadIdx.x >> 5;   // 0..7 row lane
    float s0 = 0, s1 = 0, s2 = 0, s3 = 0;
    float q0 = 0, q1 = 0, q2 = 0, q3 = 0;
    for (int r = blockIdx.x * 8 + rl; r < NN; r += gridDim.x * 8) {
        float4 v = *(const float4*)&h[(size_t)r * 128 + cg * 4];
        s0 += v.x; s1 += v.y; s2 += v.z; s3 += v.w;
        q0 += v.x * v.x; q1 += v.y * v.y; q2 += v.z * v.z; q3 += v.w * v.w;
    }
    atomicAdd(&stats[cg * 4 + 0], s0);
    atomicAdd(&stats[cg * 4 + 1], s1);
    atomicAdd(&stats[cg * 4 + 2], s2);
    atomicAdd(&stats[cg * 4 + 3], s3);
    atomicAdd(&stats[128 + cg * 4 + 0], q0);
    atomicAdd(&stats[128 + cg * 4 + 1], q1);
    atomicAdd(&stats[128 + cg * 4 + 2], q2);
    atomicAdd(&stats[128 + cg * 4 + 3], q3);
}

__global__ void k_bnapply(float* __restrict__ h, const float* __restrict__ stats,
                          const float* __restrict__ gamma, const float* __restrict__ beta) {
    int idx = blockIdx.x * 256 + threadIdx.x;
    if (idx >= NN * 32) return;
    int cg = idx & 31;
    float4 v = ((float4*)h)[idx];
    float4 sm = *(const float4*)&stats[cg * 4];
    float4 sq = *(const float4*)&stats[128 + cg * 4];
    float4 g = *(const float4*)&gamma[cg * 4];
    float4 b = *(const float4*)&beta[cg * 4];
    const float invn = 1.0f / (float)NN;
    float m, var, sc;
    float4 o;
    m = sm.x * invn; var = sq.x * invn - m * m; sc = g.x * rsqrtf(var + EPS_BN);
    o.x = fmaxf((v.x - m) * sc + b.x, 0.f);
    m = sm.y * invn; var = sq.y * invn - m * m; sc = g.y * rsqrtf(var + EPS_BN);
    o.y = fmaxf((v.y - m) * sc + b.y, 0.f);
    m = sm.z * invn; var = sq.z * invn - m * m; sc = g.z * rsqrtf(var + EPS_BN);
    o.z = fmaxf((v.z - m) * sc + b.z, 0.f);
    m = sm.w * invn; var = sq.w * invn - m * m; sc = g.w * rsqrtf(var + EPS_BN);
    o.w = fmaxf((v.w - m) * sc + b.w, 0.f);
    ((float4*)h)[idx] = o;
}

extern "C" void kernel_launch(void* const* d_in, const int* in_sizes, int n_in,
                              void* d_out, int out_size, void* d_ws, size_t ws_size,
                              hipStream_t stream) {
    const float* x  = (const float*)d_in[0];
    const int*   ei = (const int*)d_in[1];
    const int*   src = ei;        // edge_index[0]
    const int*   dst = ei + NE;   // edge_index[1]
    const float* W0 = (const float*)d_in[2];
    const float* b0 = (const float*)d_in[3];
    const float* W1 = (const float*)d_in[4];
    const float* b1 = (const float*)d_in[5];
    const float* W2 = (const float*)d_in[6];
    const float* b2 = (const float*)d_in[7];
    const float* g0 = (const float*)d_in[8];
    const float* be0 = (const float*)d_in[9];
    const float* g1 = (const float*)d_in[10];
    const float* be1 = (const float*)d_in[11];
    float* out = (float*)d_out;

    float* H    = (float*)d_ws;               // N*128
    float* A    = H + (size_t)NN * 128;       // N*128
    float* dinv = A + (size_t)NN * 128;       // N
    float* stats = dinv + NN;                 // 256

    dim3 b256(256);

    // gcn_norm
    k_init_deg<<<(NN + 255) / 256, b256, 0, stream>>>(dinv);
    k_count<<<(NE + 255) / 256, b256, 0, stream>>>(dst, dinv);
    k_rsqrt_inplace<<<(NN + 255) / 256, b256, 0, stream>>>(dinv);

    // ---- layer 0 ----
    k_gemm128<<<NN / 32, b256, 0, stream>>>(x, W0, H);
    k_selfinit<128><<<(NN * 32 + 255) / 256, b256, 0, stream>>>(H, dinv, b0, A);
    k_scatter<128><<<(int)(((long long)NE * 32 + 255) / 256), b256, 0, stream>>>(src, dst, dinv, H, A);
    k_zero_stats<<<1, b256, 0, stream>>>(stats);
    k_bnstats<<<512, b256, 0, stream>>>(A, stats);
    k_bnapply<<<(NN * 32 + 255) / 256, b256, 0, stream>>>(A, stats, g0, be0);

    // ---- layer 1 ----
    k_gemm128<<<NN / 32, b256, 0, stream>>>(A, W1, H);
    k_selfinit<128><<<(NN * 32 + 255) / 256, b256, 0, stream>>>(H, dinv, b1, A);
    k_scatter<128><<<(int)(((long long)NE * 32 + 255) / 256), b256, 0, stream>>>(src, dst, dinv, H, A);
    k_zero_stats<<<1, b256, 0, stream>>>(stats);
    k_bnstats<<<512, b256, 0, stream>>>(A, stats);
    k_bnapply<<<(NN * 32 + 255) / 256, b256, 0, stream>>>(A, stats, g1, be1);

    // ---- layer 2 (output, width 40) ----
    k_gemm40<<<(NN * 40 + 255) / 256, b256, 0, stream>>>(A, W2, H);   // H reused as [N,40]
    k_selfinit<40><<<(NN * 10 + 255) / 256, b256, 0, stream>>>(H, dinv, b2, out);
    k_scatter<40><<<(int)(((long long)NE * 10 + 255) / 256), b256, 0, stream>>>(src, dst, dinv, H, out);
}

// Round 2
// 1708.246 us; speedup vs baseline: 4.4392x; 4.4392x over previous
//
#include <hip/hip_runtime.h>

#define NN 100000
#define NE 1600000
#define EPS_BN 1e-5f
#define NP 391   // ceil(NN/256) scan partials

// ---------------- CSR build ----------------
__global__ void k_zero_int2(int* __restrict__ cnt, int* __restrict__ fill) {
    int i = blockIdx.x * 256 + threadIdx.x;
    if (i < NN) { cnt[i] = 0; fill[i] = 0; }
}

__global__ void k_hist(const int* __restrict__ dst, int* __restrict__ cnt) {
    int e = blockIdx.x * 256 + threadIdx.x;
    if (e < NE) atomicAdd(&cnt[dst[e]], 1);
}

__global__ void k_dinv(const int* __restrict__ cnt, float* __restrict__ dinv) {
    int i = blockIdx.x * 256 + threadIdx.x;
    if (i < NN) dinv[i] = rsqrtf((float)(cnt[i] + 1));   // +1 self-loop
}

__global__ __launch_bounds__(256) void k_scan1(const int* __restrict__ cnt,
                                               int* __restrict__ rowptr,
                                               int* __restrict__ partial) {
    __shared__ int sh[256];
    int i = blockIdx.x * 256 + threadIdx.x;
    int v = (i < NN) ? cnt[i] : 0;
    sh[threadIdx.x] = v;
    __syncthreads();
    for (int off = 1; off < 256; off <<= 1) {
        int t = (threadIdx.x >= off) ? sh[threadIdx.x - off] : 0;
        __syncthreads();
        sh[threadIdx.x] += t;
        __syncthreads();
    }
    if (i < NN) rowptr[i] = sh[threadIdx.x] - v;           // exclusive
    if (threadIdx.x == 255) partial[blockIdx.x] = sh[255]; // block total
}

__global__ __launch_bounds__(512) void k_scan2(int* __restrict__ partial) {
    __shared__ int sh[512];
    int tid = threadIdx.x;
    int v = (tid < NP) ? partial[tid] : 0;
    sh[tid] = v;
    __syncthreads();
    for (int off = 1; off < 512; off <<= 1) {
        int t = (tid >= off) ? sh[tid - off] : 0;
        __syncthreads();
        sh[tid] += t;
        __syncthreads();
    }
    if (tid < NP) partial[tid] = sh[tid] - v;              // exclusive
}

__global__ void k_scan3(int* __restrict__ rowptr, const int* __restrict__ partial) {
    int i = blockIdx.x * 256 + threadIdx.x;
    if (i < NN) rowptr[i] += partial[blockIdx.x];
    if (i == 0) rowptr[NN] = NE;
}

__global__ void k_fill(const int* __restrict__ src, const int* __restrict__ dst,
                       const float* __restrict__ dinv, const int* __restrict__ rowptr,
                       int* __restrict__ fill, int* __restrict__ col,
                       float* __restrict__ enrm) {
    int e = blockIdx.x * 256 + threadIdx.x;
    if (e >= NE) return;
    int s = src[e], d = dst[e];
    int pos = rowptr[d] + atomicAdd(&fill[d], 1);
    col[pos] = s;
    enrm[pos] = dinv[s] * dinv[d];
}

// ---------------- GEMM: out[N,128] = in[N,128] @ W[128,128] ----------------
__global__ __launch_bounds__(256) void k_gemm128(const float* __restrict__ in,
                                                 const float* __restrict__ W,
                                                 float* __restrict__ out) {
    __shared__ float xs[32][128];
    const int tid = threadIdx.x;
    const int row0 = blockIdx.x * 32;
    for (int i = tid; i < 32 * 32; i += 256)
        ((float4*)xs)[i] = ((const float4*)(in + (size_t)row0 * 128))[i];
    __syncthreads();

    const int cg = tid & 31;
    const int rg = tid >> 5;
    float acc[4][4] = {};
    const float* Wp = W + cg * 4;
    for (int k = 0; k < 128; k += 4) {
        float xr[4][4], wv[4][4];
        #pragma unroll
        for (int i = 0; i < 4; ++i)
            *(float4*)xr[i] = *(const float4*)&xs[rg * 4 + i][k];
        #pragma unroll
        for (int kk = 0; kk < 4; ++kk)
            *(float4*)wv[kk] = *(const float4*)&Wp[(size_t)(k + kk) * 128];
        #pragma unroll
        for (int i = 0; i < 4; ++i)
            #pragma unroll
            for (int kk = 0; kk < 4; ++kk)
                #pragma unroll
                for (int j = 0; j < 4; ++j)
                    acc[i][j] += xr[i][kk] * wv[kk][j];
    }
    #pragma unroll
    for (int i = 0; i < 4; ++i) {
        float4 o = {acc[i][0], acc[i][1], acc[i][2], acc[i][3]};
        *(float4*)&out[(size_t)(row0 + rg * 4 + i) * 128 + cg * 4] = o;
    }
}

// ---------------- GEMM: out[N,40] = in[N,128] @ W[128,40] ----------------
__global__ void k_gemm40(const float* __restrict__ in, const float* __restrict__ W,
                         float* __restrict__ out) {
    int idx = blockIdx.x * 256 + threadIdx.x;
    if (idx >= NN * 40) return;
    int row = idx / 40, col = idx - row * 40;
    const float* xp = in + (size_t)row * 128;
    float acc = 0.f;
    #pragma unroll 8
    for (int k = 0; k < 128; ++k) acc += xp[k] * W[k * 40 + col];
    out[idx] = acc;
}

// ---------------- CSR gather aggregation, F=128 ----------------
// one 64-lane wave per node; lane owns float2 (2 cols); per edge the wave
// reads one contiguous 512B row of h (L3-resident: h = 51MB < 256MB L3)
__global__ __launch_bounds__(256) void k_gather128(
    const float* __restrict__ h, const float* __restrict__ dinv,
    const int* __restrict__ rowptr, const int* __restrict__ col,
    const float* __restrict__ enrm, const float* __restrict__ bias,
    float* __restrict__ agg) {
    int node = blockIdx.x * 4 + (threadIdx.x >> 6);
    if (node >= NN) return;
    int lane = threadIdx.x & 63;
    int c = lane * 2;
    float d = dinv[node];
    float s = d * d;
    float2 hv = *(const float2*)(h + (size_t)node * 128 + c);
    float2 acc;
    acc.x = hv.x * s + bias[c];
    acc.y = hv.y * s + bias[c + 1];
    int e0 = rowptr[node], e1 = rowptr[node + 1];
    for (int e = e0; e < e1; ++e) {
        int sn = col[e];
        float w = enrm[e];
        float2 v = *(const float2*)(h + (size_t)sn * 128 + c);
        acc.x += v.x * w;
        acc.y += v.y * w;
    }
    *(float2*)(agg + (size_t)node * 128 + c) = acc;
}

// ---------------- CSR gather aggregation, F=40 (thread per output elem) ----
__global__ void k_gather40(
    const float* __restrict__ h, const float* __restrict__ dinv,
    const int* __restrict__ rowptr, const int* __restrict__ col,
    const float* __restrict__ enrm, const float* __restrict__ bias,
    float* __restrict__ out) {
    int idx = blockIdx.x * 256 + threadIdx.x;
    if (idx >= NN * 40) return;
    int node = idx / 40, c = idx - node * 40;
    float d = dinv[node];
    float acc = h[(size_t)node * 40 + c] * d * d + bias[c];
    int e0 = rowptr[node], e1 = rowptr[node + 1];
    for (int e = e0; e < e1; ++e)
        acc += h[(size_t)col[e] * 40 + c] * enrm[e];
    out[idx] = acc;
}

// ---------------- batchnorm ----------------
__global__ void k_zero_stats(float* __restrict__ stats) {
    stats[threadIdx.x] = 0.f;
}

__global__ __launch_bounds__(256) void k_bnstats(const float* __restrict__ h,
                                                 float* __restrict__ stats) {
    int cg = threadIdx.x & 31;
    int rl = threadIdx.x >> 5;
    float s0 = 0, s1 = 0, s2 = 0, s3 = 0;
    float q0 = 0, q1 = 0, q2 = 0, q3 = 0;
    for (int r = blockIdx.x * 8 + rl; r < NN; r += gridDim.x * 8) {
        float4 v = *(const float4*)&h[(size_t)r * 128 + cg * 4];
        s0 += v.x; s1 += v.y; s2 += v.z; s3 += v.w;
        q0 += v.x * v.x; q1 += v.y * v.y; q2 += v.z * v.z; q3 += v.w * v.w;
    }
    atomicAdd(&stats[cg * 4 + 0], s0);
    atomicAdd(&stats[cg * 4 + 1], s1);
    atomicAdd(&stats[cg * 4 + 2], s2);
    atomicAdd(&stats[cg * 4 + 3], s3);
    atomicAdd(&stats[128 + cg * 4 + 0], q0);
    atomicAdd(&stats[128 + cg * 4 + 1], q1);
    atomicAdd(&stats[128 + cg * 4 + 2], q2);
    atomicAdd(&stats[128 + cg * 4 + 3], q3);
}

__global__ void k_bnapply(float* __restrict__ h, const float* __restrict__ stats,
                          const float* __restrict__ gamma, const float* __restrict__ beta) {
    int idx = blockIdx.x * 256 + threadIdx.x;
    if (idx >= NN * 32) return;
    int cg = idx & 31;
    float4 v = ((float4*)h)[idx];
    float4 sm = *(const float4*)&stats[cg * 4];
    float4 sq = *(const float4*)&stats[128 + cg * 4];
    float4 g = *(const float4*)&gamma[cg * 4];
    float4 b = *(const float4*)&beta[cg * 4];
    const float invn = 1.0f / (float)NN;
    float m, var, sc;
    float4 o;
    m = sm.x * invn; var = sq.x * invn - m * m; sc = g.x * rsqrtf(var + EPS_BN);
    o.x = fmaxf((v.x - m) * sc + b.x, 0.f);
    m = sm.y * invn; var = sq.y * invn - m * m; sc = g.y * rsqrtf(var + EPS_BN);
    o.y = fmaxf((v.y - m) * sc + b.y, 0.f);
    m = sm.z * invn; var = sq.z * invn - m * m; sc = g.z * rsqrtf(var + EPS_BN);
    o.z = fmaxf((v.z - m) * sc + b.z, 0.f);
    m = sm.w * invn; var = sq.w * invn - m * m; sc = g.w * rsqrtf(var + EPS_BN);
    o.w = fmaxf((v.w - m) * sc + b.w, 0.f);
    ((float4*)h)[idx] = o;
}

extern "C" void kernel_launch(void* const* d_in, const int* in_sizes, int n_in,
                              void* d_out, int out_size, void* d_ws, size_t ws_size,
                              hipStream_t stream) {
    const float* x  = (const float*)d_in[0];
    const int*   ei = (const int*)d_in[1];
    const int*   src = ei;        // edge_index[0]
    const int*   dst = ei + NE;   // edge_index[1]
    const float* W0 = (const float*)d_in[2];
    const float* b0 = (const float*)d_in[3];
    const float* W1 = (const float*)d_in[4];
    const float* b1 = (const float*)d_in[5];
    const float* W2 = (const float*)d_in[6];
    const float* b2 = (const float*)d_in[7];
    const float* g0 = (const float*)d_in[8];
    const float* be0 = (const float*)d_in[9];
    const float* g1 = (const float*)d_in[10];
    const float* be1 = (const float*)d_in[11];
    float* out = (float*)d_out;

    // workspace layout (~117 MB)
    float* H      = (float*)d_ws;                 // N*128
    float* A      = H + (size_t)NN * 128;         // N*128
    float* dinv   = A + (size_t)NN * 128;         // N
    float* stats  = dinv + NN;                    // 256
    int*   cnt    = (int*)(stats + 256);          // N
    int*   fill   = cnt + NN;                     // N
    int*   rowptr = fill + NN;                    // N+1
    int*   partial= rowptr + NN + 1;              // 512
    int*   col    = partial + 512;                // E
    float* enrm   = (float*)(col + NE);           // E

    dim3 b256(256);
    int gN = (NN + 255) / 256;
    int gE = (NE + 255) / 256;

    // ---- CSR build + norm ----
    k_zero_int2<<<gN, b256, 0, stream>>>(cnt, fill);
    k_hist<<<gE, b256, 0, stream>>>(dst, cnt);
    k_dinv<<<gN, b256, 0, stream>>>(cnt, dinv);
    k_scan1<<<NP, b256, 0, stream>>>(cnt, rowptr, partial);
    k_scan2<<<1, 512, 0, stream>>>(partial);
    k_scan3<<<NP, b256, 0, stream>>>(rowptr, partial);
    k_fill<<<gE, b256, 0, stream>>>(src, dst, dinv, rowptr, fill, col, enrm);

    int gG128 = (NN + 3) / 4;

    // ---- layer 0 ----
    k_gemm128<<<NN / 32, b256, 0, stream>>>(x, W0, H);
    k_gather128<<<gG128, b256, 0, stream>>>(H, dinv, rowptr, col, enrm, b0, A);
    k_zero_stats<<<1, b256, 0, stream>>>(stats);
    k_bnstats<<<512, b256, 0, stream>>>(A, stats);
    k_bnapply<<<(NN * 32 + 255) / 256, b256, 0, stream>>>(A, stats, g0, be0);

    // ---- layer 1 ----
    k_gemm128<<<NN / 32, b256, 0, stream>>>(A, W1, H);
    k_gather128<<<gG128, b256, 0, stream>>>(H, dinv, rowptr, col, enrm, b1, A);
    k_zero_stats<<<1, b256, 0, stream>>>(stats);
    k_bnstats<<<512, b256, 0, stream>>>(A, stats);
    k_bnapply<<<(NN * 32 + 255) / 256, b256, 0, stream>>>(A, stats, g1, be1);

    // ---- layer 2 (output, width 40) ----
    k_gemm40<<<(NN * 40 + 255) / 256, b256, 0, stream>>>(A, W2, H);   // H as [N,40]
    k_gather40<<<(NN * 40 + 255) / 256, b256, 0, stream>>>(H, dinv, rowptr, col, enrm, b2, out);
}

// Round 3
// 889.147 us; speedup vs baseline: 8.5287x; 1.9212x over previous
//
#include <hip/hip_runtime.h>

#define NN 100000
#define NE 1600000
#define EPS_BN 1e-5f
#define NP 391   // ceil(NN/256) scan partials

// ---------------- CSR build ----------------
__global__ void k_zero_int2(int* __restrict__ cnt, int* __restrict__ fill) {
    int i = blockIdx.x * 256 + threadIdx.x;
    if (i < NN) { cnt[i] = 0; fill[i] = 0; }
}

__global__ void k_hist(const int* __restrict__ dst, int* __restrict__ cnt) {
    int e = blockIdx.x * 256 + threadIdx.x;
    if (e < NE) atomicAdd(&cnt[dst[e]], 1);
}

__global__ void k_dinv(const int* __restrict__ cnt, float* __restrict__ dinv) {
    int i = blockIdx.x * 256 + threadIdx.x;
    if (i < NN) dinv[i] = rsqrtf((float)(cnt[i] + 1));   // +1 self-loop
}

__global__ __launch_bounds__(256) void k_scan1(const int* __restrict__ cnt,
                                               int* __restrict__ rowptr,
                                               int* __restrict__ partial) {
    __shared__ int sh[256];
    int i = blockIdx.x * 256 + threadIdx.x;
    int v = (i < NN) ? cnt[i] : 0;
    sh[threadIdx.x] = v;
    __syncthreads();
    for (int off = 1; off < 256; off <<= 1) {
        int t = (threadIdx.x >= off) ? sh[threadIdx.x - off] : 0;
        __syncthreads();
        sh[threadIdx.x] += t;
        __syncthreads();
    }
    if (i < NN) rowptr[i] = sh[threadIdx.x] - v;           // exclusive
    if (threadIdx.x == 255) partial[blockIdx.x] = sh[255]; // block total
}

__global__ __launch_bounds__(512) void k_scan2(int* __restrict__ partial) {
    __shared__ int sh[512];
    int tid = threadIdx.x;
    int v = (tid < NP) ? partial[tid] : 0;
    sh[tid] = v;
    __syncthreads();
    for (int off = 1; off < 512; off <<= 1) {
        int t = (tid >= off) ? sh[tid - off] : 0;
        __syncthreads();
        sh[tid] += t;
        __syncthreads();
    }
    if (tid < NP) partial[tid] = sh[tid] - v;              // exclusive
}

__global__ void k_scan3(int* __restrict__ rowptr, const int* __restrict__ partial) {
    int i = blockIdx.x * 256 + threadIdx.x;
    if (i < NN) rowptr[i] += partial[blockIdx.x];
    if (i == 0) rowptr[NN] = NE;
}

__global__ void k_fill(const int* __restrict__ src, const int* __restrict__ dst,
                       const float* __restrict__ dinv, const int* __restrict__ rowptr,
                       int* __restrict__ fill, int* __restrict__ col,
                       float* __restrict__ enrm) {
    int e = blockIdx.x * 256 + threadIdx.x;
    if (e >= NE) return;
    int s = src[e], d = dst[e];
    int pos = rowptr[d] + atomicAdd(&fill[d], 1);
    col[pos] = s;
    enrm[pos] = dinv[s] * dinv[d];
}

// ---------------- GEMM: out[N,128] = bn(in)[N,128] @ W[128,128] ----------------
// BN: v -> relu(v*bnsc[c] + bnsh[c]) applied while staging into LDS
template <bool BN>
__global__ __launch_bounds__(256) void k_gemm128(const float* __restrict__ in,
                                                 const float* __restrict__ W,
                                                 float* __restrict__ out,
                                                 const float* __restrict__ bnsc,
                                                 const float* __restrict__ bnsh) {
    __shared__ float xs[32][128];
    const int tid = threadIdx.x;
    const int row0 = blockIdx.x * 32;
    for (int i = tid; i < 32 * 32; i += 256) {
        float4 v = ((const float4*)(in + (size_t)row0 * 128))[i];
        if (BN) {
            int c = (i & 31) * 4;
            float4 sc = *(const float4*)&bnsc[c];
            float4 sh = *(const float4*)&bnsh[c];
            v.x = fmaxf(v.x * sc.x + sh.x, 0.f);
            v.y = fmaxf(v.y * sc.y + sh.y, 0.f);
            v.z = fmaxf(v.z * sc.z + sh.z, 0.f);
            v.w = fmaxf(v.w * sc.w + sh.w, 0.f);
        }
        ((float4*)xs)[i] = v;
    }
    __syncthreads();

    const int cg = tid & 31;
    const int rg = tid >> 5;
    float acc[4][4] = {};
    const float* Wp = W + cg * 4;
    for (int k = 0; k < 128; k += 4) {
        float xr[4][4], wv[4][4];
        #pragma unroll
        for (int i = 0; i < 4; ++i)
            *(float4*)xr[i] = *(const float4*)&xs[rg * 4 + i][k];
        #pragma unroll
        for (int kk = 0; kk < 4; ++kk)
            *(float4*)wv[kk] = *(const float4*)&Wp[(size_t)(k + kk) * 128];
        #pragma unroll
        for (int i = 0; i < 4; ++i)
            #pragma unroll
            for (int kk = 0; kk < 4; ++kk)
                #pragma unroll
                for (int j = 0; j < 4; ++j)
                    acc[i][j] += xr[i][kk] * wv[kk][j];
    }
    #pragma unroll
    for (int i = 0; i < 4; ++i) {
        float4 o = {acc[i][0], acc[i][1], acc[i][2], acc[i][3]};
        *(float4*)&out[(size_t)(row0 + rg * 4 + i) * 128 + cg * 4] = o;
    }
}

// ---------------- GEMM: out[N,40] = bn(in)[N,128] @ W[128,40] ----------------
__global__ void k_gemm40(const float* __restrict__ in, const float* __restrict__ W,
                         float* __restrict__ out,
                         const float* __restrict__ bnsc,
                         const float* __restrict__ bnsh) {
    int idx = blockIdx.x * 256 + threadIdx.x;
    if (idx >= NN * 40) return;
    int row = idx / 40, col = idx - row * 40;
    const float* xp = in + (size_t)row * 128;
    float acc = 0.f;
    #pragma unroll 8
    for (int k = 0; k < 128; ++k) {
        float v = fmaxf(xp[k] * bnsc[k] + bnsh[k], 0.f);
        acc += v * W[k * 40 + col];
    }
    out[idx] = acc;
}

// ---------------- CSR gather aggregation, F=128 ----------------
__global__ __launch_bounds__(256) void k_gather128(
    const float* __restrict__ h, const float* __restrict__ dinv,
    const int* __restrict__ rowptr, const int* __restrict__ col,
    const float* __restrict__ enrm, const float* __restrict__ bias,
    float* __restrict__ agg) {
    int node = blockIdx.x * 4 + (threadIdx.x >> 6);
    if (node >= NN) return;
    int lane = threadIdx.x & 63;
    int c = lane * 2;
    float d = dinv[node];
    float s = d * d;
    float2 hv = *(const float2*)(h + (size_t)node * 128 + c);
    float2 acc;
    acc.x = hv.x * s + bias[c];
    acc.y = hv.y * s + bias[c + 1];
    int e0 = rowptr[node], e1 = rowptr[node + 1];
    for (int e = e0; e < e1; ++e) {
        int sn = col[e];
        float w = enrm[e];
        float2 v = *(const float2*)(h + (size_t)sn * 128 + c);
        acc.x += v.x * w;
        acc.y += v.y * w;
    }
    *(float2*)(agg + (size_t)node * 128 + c) = acc;
}

// ---------------- CSR gather aggregation, F=40 ----------------
__global__ void k_gather40(
    const float* __restrict__ h, const float* __restrict__ dinv,
    const int* __restrict__ rowptr, const int* __restrict__ col,
    const float* __restrict__ enrm, const float* __restrict__ bias,
    float* __restrict__ out) {
    int idx = blockIdx.x * 256 + threadIdx.x;
    if (idx >= NN * 40) return;
    int node = idx / 40, c = idx - node * 40;
    float d = dinv[node];
    float acc = h[(size_t)node * 40 + c] * d * d + bias[c];
    int e0 = rowptr[node], e1 = rowptr[node + 1];
    for (int e = e0; e < e1; ++e)
        acc += h[(size_t)col[e] * 40 + c] * enrm[e];
    out[idx] = acc;
}

// ---------------- batchnorm stats (block-reduced, then atomics) ----------------
__global__ void k_zero_stats(float* __restrict__ stats) {
    stats[threadIdx.x] = 0.f;   // 256: [0:128) sum, [128:256) sumsq
}

__global__ __launch_bounds__(256) void k_bnstats(const float* __restrict__ h,
                                                 float* __restrict__ stats) {
    __shared__ float shs[8][132];
    __shared__ float shq[8][132];
    int cg = threadIdx.x & 31;
    int rl = threadIdx.x >> 5;
    float s0 = 0, s1 = 0, s2 = 0, s3 = 0;
    float q0 = 0, q1 = 0, q2 = 0, q3 = 0;
    for (int r = blockIdx.x * 8 + rl; r < NN; r += gridDim.x * 8) {
        float4 v = *(const float4*)&h[(size_t)r * 128 + cg * 4];
        s0 += v.x; s1 += v.y; s2 += v.z; s3 += v.w;
        q0 += v.x * v.x; q1 += v.y * v.y; q2 += v.z * v.z; q3 += v.w * v.w;
    }
    shs[rl][cg * 4 + 0] = s0; shs[rl][cg * 4 + 1] = s1;
    shs[rl][cg * 4 + 2] = s2; shs[rl][cg * 4 + 3] = s3;
    shq[rl][cg * 4 + 0] = q0; shq[rl][cg * 4 + 1] = q1;
    shq[rl][cg * 4 + 2] = q2; shq[rl][cg * 4 + 3] = q3;
    __syncthreads();
    if (threadIdx.x < 128) {
        float ss = 0, qq = 0;
        #pragma unroll
        for (int r = 0; r < 8; ++r) { ss += shs[r][threadIdx.x]; qq += shq[r][threadIdx.x]; }
        atomicAdd(&stats[threadIdx.x], ss);
        atomicAdd(&stats[128 + threadIdx.x], qq);
    }
}

// fold stats + gamma/beta into per-column scale/shift
__global__ void k_bnfinal(const float* __restrict__ stats,
                          const float* __restrict__ gamma, const float* __restrict__ beta,
                          float* __restrict__ bnsc, float* __restrict__ bnsh) {
    int c = threadIdx.x;
    if (c >= 128) return;
    const float invn = 1.0f / (float)NN;
    float m = stats[c] * invn;
    float var = stats[128 + c] * invn - m * m;
    float sc = gamma[c] * rsqrtf(var + EPS_BN);
    bnsc[c] = sc;
    bnsh[c] = beta[c] - m * sc;
}

extern "C" void kernel_launch(void* const* d_in, const int* in_sizes, int n_in,
                              void* d_out, int out_size, void* d_ws, size_t ws_size,
                              hipStream_t stream) {
    const float* x  = (const float*)d_in[0];
    const int*   ei = (const int*)d_in[1];
    const int*   src = ei;        // edge_index[0]
    const int*   dst = ei + NE;   // edge_index[1]
    const float* W0 = (const float*)d_in[2];
    const float* b0 = (const float*)d_in[3];
    const float* W1 = (const float*)d_in[4];
    const float* b1 = (const float*)d_in[5];
    const float* W2 = (const float*)d_in[6];
    const float* b2 = (const float*)d_in[7];
    const float* g0 = (const float*)d_in[8];
    const float* be0 = (const float*)d_in[9];
    const float* g1 = (const float*)d_in[10];
    const float* be1 = (const float*)d_in[11];
    float* out = (float*)d_out;

    // workspace layout
    float* H      = (float*)d_ws;                 // N*128
    float* A      = H + (size_t)NN * 128;         // N*128
    float* dinv   = A + (size_t)NN * 128;         // N
    float* stats  = dinv + NN;                    // 256
    float* bnsc   = stats + 256;                  // 128
    float* bnsh   = bnsc + 128;                   // 128
    int*   cnt    = (int*)(bnsh + 128);           // N
    int*   fill   = cnt + NN;                     // N
    int*   rowptr = fill + NN;                    // N+1
    int*   partial= rowptr + NN + 1;              // 512
    int*   col    = partial + 512;                // E
    float* enrm   = (float*)(col + NE);           // E

    dim3 b256(256);
    int gN = (NN + 255) / 256;
    int gE = (NE + 255) / 256;

    // ---- CSR build + norm ----
    k_zero_int2<<<gN, b256, 0, stream>>>(cnt, fill);
    k_hist<<<gE, b256, 0, stream>>>(dst, cnt);
    k_dinv<<<gN, b256, 0, stream>>>(cnt, dinv);
    k_scan1<<<NP, b256, 0, stream>>>(cnt, rowptr, partial);
    k_scan2<<<1, 512, 0, stream>>>(partial);
    k_scan3<<<NP, b256, 0, stream>>>(rowptr, partial);
    k_fill<<<gE, b256, 0, stream>>>(src, dst, dinv, rowptr, fill, col, enrm);

    int gG128 = (NN + 3) / 4;

    // ---- layer 0 ----
    k_gemm128<false><<<NN / 32, b256, 0, stream>>>(x, W0, H, nullptr, nullptr);
    k_gather128<<<gG128, b256, 0, stream>>>(H, dinv, rowptr, col, enrm, b0, A);
    k_zero_stats<<<1, b256, 0, stream>>>(stats);
    k_bnstats<<<512, b256, 0, stream>>>(A, stats);
    k_bnfinal<<<1, 128, 0, stream>>>(stats, g0, be0, bnsc, bnsh);

    // ---- layer 1 (BN0+relu fused into gemm load) ----
    k_gemm128<true><<<NN / 32, b256, 0, stream>>>(A, W1, H, bnsc, bnsh);
    k_gather128<<<gG128, b256, 0, stream>>>(H, dinv, rowptr, col, enrm, b1, A);
    k_zero_stats<<<1, b256, 0, stream>>>(stats);
    k_bnstats<<<512, b256, 0, stream>>>(A, stats);
    k_bnfinal<<<1, 128, 0, stream>>>(stats, g1, be1, bnsc, bnsh);

    // ---- layer 2 (BN1+relu fused into gemm40 load) ----
    k_gemm40<<<(NN * 40 + 255) / 256, b256, 0, stream>>>(A, W2, H, bnsc, bnsh);  // H as [N,40]
    k_gather40<<<(NN * 40 + 255) / 256, b256, 0, stream>>>(H, dinv, rowptr, col, enrm, b2, out);
}

// Round 4
// 612.261 us; speedup vs baseline: 12.3856x; 1.4522x over previous
//
#include <hip/hip_runtime.h>

#define NN 100000
#define NE 1600000
#define EPS_BN 1e-5f
#define NP 391   // ceil(NN/256) scan partials

typedef __attribute__((ext_vector_type(8))) short short8v;
typedef __attribute__((ext_vector_type(4))) float f32x4;

__device__ __forceinline__ unsigned short f2bf(float f) {
    unsigned u = __float_as_uint(f);
    u += 0x7fff + ((u >> 16) & 1);          // RTNE
    return (unsigned short)(u >> 16);
}
__device__ __forceinline__ float bf2f(unsigned short h) {
    return __uint_as_float((unsigned)h << 16);
}

// ---------------- CSR build ----------------
__global__ void k_zero_int(int* __restrict__ cnt) {
    int i = blockIdx.x * 256 + threadIdx.x;
    if (i < NN) cnt[i] = 0;
}

__global__ void k_hist(const int* __restrict__ dst, int* __restrict__ cnt) {
    int e = blockIdx.x * 256 + threadIdx.x;
    if (e < NE) atomicAdd(&cnt[dst[e]], 1);
}

__global__ void k_dinv(const int* __restrict__ cnt, float* __restrict__ dinv) {
    int i = blockIdx.x * 256 + threadIdx.x;
    if (i < NN) dinv[i] = rsqrtf((float)(cnt[i] + 1));   // +1 self-loop
}

__global__ __launch_bounds__(256) void k_scan1(const int* __restrict__ cnt,
                                               int* __restrict__ rowptr,
                                               int* __restrict__ partial) {
    __shared__ int sh[256];
    int i = blockIdx.x * 256 + threadIdx.x;
    int v = (i < NN) ? cnt[i] : 0;
    sh[threadIdx.x] = v;
    __syncthreads();
    for (int off = 1; off < 256; off <<= 1) {
        int t = (threadIdx.x >= off) ? sh[threadIdx.x - off] : 0;
        __syncthreads();
        sh[threadIdx.x] += t;
        __syncthreads();
    }
    if (i < NN) rowptr[i] = sh[threadIdx.x] - v;           // exclusive
    if (threadIdx.x == 255) partial[blockIdx.x] = sh[255]; // block total
}

__global__ __launch_bounds__(512) void k_scan2(int* __restrict__ partial) {
    __shared__ int sh[512];
    int tid = threadIdx.x;
    int v = (tid < NP) ? partial[tid] : 0;
    sh[tid] = v;
    __syncthreads();
    for (int off = 1; off < 512; off <<= 1) {
        int t = (tid >= off) ? sh[tid - off] : 0;
        __syncthreads();
        sh[tid] += t;
        __syncthreads();
    }
    if (tid < NP) partial[tid] = sh[tid] - v;              // exclusive
}

__global__ void k_scan3(int* __restrict__ rowptr, const int* __restrict__ partial,
                        int* __restrict__ fill) {
    int i = blockIdx.x * 256 + threadIdx.x;
    if (i < NN) {
        int v = rowptr[i] + partial[blockIdx.x];
        rowptr[i] = v;
        fill[i] = v;                                       // fill cursor = row start
    }
    if (i == 0) rowptr[NN] = NE;
}

__global__ void k_fill(const int* __restrict__ src, const int* __restrict__ dst,
                       const float* __restrict__ dinv,
                       int* __restrict__ fill, int2* __restrict__ ce) {
    int e = blockIdx.x * 256 + threadIdx.x;
    if (e >= NE) return;
    int s = src[e], d = dst[e];
    int pos = atomicAdd(&fill[d], 1);
    int2 p;
    p.x = s;
    p.y = __float_as_int(dinv[s] * dinv[d]);
    ce[pos] = p;
}

// ---------------- W convert + transpose: Wt[c][k] = bf16(W[k][c]) ----------------
__global__ void k_wconv(const float* __restrict__ W, unsigned short* __restrict__ Wt) {
    int idx = blockIdx.x * 256 + threadIdx.x;
    if (idx >= 128 * 128) return;
    int k = idx >> 7, c = idx & 127;
    Wt[c * 128 + k] = f2bf(W[idx]);
}

// ---------------- MFMA GEMM: outb[N,128](bf16) = bn(in)[N,128] @ W ----------------
// block = 256 thr (4 waves), 32 rows/block; wave w owns cols w*32..w*32+31
#define XPAD 136   // LDS row stride in ushorts: 272B = 68 words, 68%32=4 -> 2-way max
template <bool BN>
__global__ __launch_bounds__(256) void k_gemm128_mfma(
    const float* __restrict__ in, const unsigned short* __restrict__ Wt,
    unsigned short* __restrict__ outb,
    const float* __restrict__ bnsc, const float* __restrict__ bnsh) {
    __shared__ unsigned short xs[32 * XPAD];
    const int tid = threadIdx.x;
    const int row0 = blockIdx.x * 32;
    // stage 32 rows, convert fp32 -> bf16 (optionally BN+ReLU first)
    for (int i = tid; i < 1024; i += 256) {
        float4 v = ((const float4*)(in + (size_t)row0 * 128))[i];
        int c4 = (i & 31) * 4;
        if (BN) {
            float4 sc = *(const float4*)&bnsc[c4];
            float4 sh = *(const float4*)&bnsh[c4];
            v.x = fmaxf(v.x * sc.x + sh.x, 0.f);
            v.y = fmaxf(v.y * sc.y + sh.y, 0.f);
            v.z = fmaxf(v.z * sc.z + sh.z, 0.f);
            v.w = fmaxf(v.w * sc.w + sh.w, 0.f);
        }
        ushort4 b;
        b.x = f2bf(v.x); b.y = f2bf(v.y); b.z = f2bf(v.z); b.w = f2bf(v.w);
        *(ushort4*)&xs[(i >> 5) * XPAD + c4] = b;
    }
    __syncthreads();

    const int w = tid >> 6;         // wave 0..3
    const int L = tid & 63;
    const int l15 = L & 15;
    const int l4 = L >> 4;          // 0..3
    f32x4 acc[2][2] = {{{0.f, 0.f, 0.f, 0.f}, {0.f, 0.f, 0.f, 0.f}},
                       {{0.f, 0.f, 0.f, 0.f}, {0.f, 0.f, 0.f, 0.f}}};
    const unsigned short* Wb0 = Wt + (size_t)(w * 32 + l15) * 128;
    const unsigned short* Wb1 = Wt + (size_t)(w * 32 + 16 + l15) * 128;
    #pragma unroll
    for (int kk = 0; kk < 4; ++kk) {
        int k0 = kk * 32 + l4 * 8;
        short8v a0 = *(const short8v*)&xs[l15 * XPAD + k0];
        short8v a1 = *(const short8v*)&xs[(16 + l15) * XPAD + k0];
        short8v b0 = *(const short8v*)&Wb0[k0];
        short8v b1 = *(const short8v*)&Wb1[k0];
        acc[0][0] = __builtin_amdgcn_mfma_f32_16x16x32_bf16(a0, b0, acc[0][0], 0, 0, 0);
        acc[0][1] = __builtin_amdgcn_mfma_f32_16x16x32_bf16(a0, b1, acc[0][1], 0, 0, 0);
        acc[1][0] = __builtin_amdgcn_mfma_f32_16x16x32_bf16(a1, b0, acc[1][0], 0, 0, 0);
        acc[1][1] = __builtin_amdgcn_mfma_f32_16x16x32_bf16(a1, b1, acc[1][1], 0, 0, 0);
    }
    // C/D layout: col = lane&15, row = (lane>>4)*4 + reg
    #pragma unroll
    for (int h = 0; h < 2; ++h)
        #pragma unroll
        for (int c = 0; c < 2; ++c) {
            int colg = w * 32 + c * 16 + l15;
            #pragma unroll
            for (int r = 0; r < 4; ++r) {
                int rowg = row0 + h * 16 + l4 * 4 + r;
                outb[(size_t)rowg * 128 + colg] = f2bf(acc[h][c][r]);
            }
        }
}

// ---------------- GEMM: out[N,40] = bn(in)[N,128] @ W[128,40] ----------------
__global__ void k_gemm40(const float* __restrict__ in, const float* __restrict__ W,
                         float* __restrict__ out,
                         const float* __restrict__ bnsc,
                         const float* __restrict__ bnsh) {
    int idx = blockIdx.x * 256 + threadIdx.x;
    if (idx >= NN * 40) return;
    int row = idx / 40, col = idx - row * 40;
    const float* xp = in + (size_t)row * 128;
    float acc = 0.f;
    #pragma unroll 8
    for (int k = 0; k < 128; ++k) {
        float v = fmaxf(xp[k] * bnsc[k] + bnsh[k], 0.f);
        acc += v * W[k * 40 + col];
    }
    out[idx] = acc;
}

// ---------------- CSR gather (bf16 h rows, 256B each), F=128 ----------------
__global__ __launch_bounds__(256) void k_gather128b(
    const unsigned short* __restrict__ hb, const float* __restrict__ dinv,
    const int* __restrict__ rowptr, const int2* __restrict__ ce,
    const float* __restrict__ bias, float* __restrict__ agg) {
    int node = blockIdx.x * 4 + (threadIdx.x >> 6);
    if (node >= NN) return;
    int lane = threadIdx.x & 63;
    int c = lane * 2;
    float d = dinv[node];
    float s = d * d;
    ushort2 hv = *(const ushort2*)(hb + (size_t)node * 128 + c);
    float2 acc;
    acc.x = bf2f(hv.x) * s + bias[c];
    acc.y = bf2f(hv.y) * s + bias[c + 1];
    int e = rowptr[node], e1 = rowptr[node + 1];
    for (; e + 4 <= e1; e += 4) {
        int2 p0 = ce[e], p1 = ce[e + 1], p2 = ce[e + 2], p3 = ce[e + 3];
        ushort2 v0 = *(const ushort2*)(hb + (size_t)p0.x * 128 + c);
        ushort2 v1 = *(const ushort2*)(hb + (size_t)p1.x * 128 + c);
        ushort2 v2 = *(const ushort2*)(hb + (size_t)p2.x * 128 + c);
        ushort2 v3 = *(const ushort2*)(hb + (size_t)p3.x * 128 + c);
        float w0 = __int_as_float(p0.y), w1 = __int_as_float(p1.y);
        float w2 = __int_as_float(p2.y), w3 = __int_as_float(p3.y);
        acc.x += bf2f(v0.x) * w0; acc.y += bf2f(v0.y) * w0;
        acc.x += bf2f(v1.x) * w1; acc.y += bf2f(v1.y) * w1;
        acc.x += bf2f(v2.x) * w2; acc.y += bf2f(v2.y) * w2;
        acc.x += bf2f(v3.x) * w3; acc.y += bf2f(v3.y) * w3;
    }
    for (; e < e1; ++e) {
        int2 p = ce[e];
        ushort2 v = *(const ushort2*)(hb + (size_t)p.x * 128 + c);
        float w = __int_as_float(p.y);
        acc.x += bf2f(v.x) * w; acc.y += bf2f(v.y) * w;
    }
    *(float2*)(agg + (size_t)node * 128 + c) = acc;
}

// ---------------- CSR gather, F=40 (fp32) ----------------
__global__ void k_gather40(
    const float* __restrict__ h, const float* __restrict__ dinv,
    const int* __restrict__ rowptr, const int2* __restrict__ ce,
    const float* __restrict__ bias, float* __restrict__ out) {
    int idx = blockIdx.x * 256 + threadIdx.x;
    if (idx >= NN * 40) return;
    int node = idx / 40, c = idx - node * 40;
    float d = dinv[node];
    float acc = h[(size_t)node * 40 + c] * d * d + bias[c];
    int e = rowptr[node], e1 = rowptr[node + 1];
    for (; e + 2 <= e1; e += 2) {
        int2 p0 = ce[e], p1 = ce[e + 1];
        float v0 = h[(size_t)p0.x * 40 + c];
        float v1 = h[(size_t)p1.x * 40 + c];
        acc += v0 * __int_as_float(p0.y) + v1 * __int_as_float(p1.y);
    }
    for (; e < e1; ++e) {
        int2 p = ce[e];
        acc += h[(size_t)p.x * 40 + c] * __int_as_float(p.y);
    }
    out[idx] = acc;
}

// ---------------- batchnorm stats ----------------
__global__ void k_zero_stats(float* __restrict__ stats) {
    stats[threadIdx.x] = 0.f;   // 256: [0:128) sum, [128:256) sumsq
}

__global__ __launch_bounds__(256) void k_bnstats(const float* __restrict__ h,
                                                 float* __restrict__ stats) {
    __shared__ float shs[8][132];
    __shared__ float shq[8][132];
    int cg = threadIdx.x & 31;
    int rl = threadIdx.x >> 5;
    float s0 = 0, s1 = 0, s2 = 0, s3 = 0;
    float q0 = 0, q1 = 0, q2 = 0, q3 = 0;
    for (int r = blockIdx.x * 8 + rl; r < NN; r += gridDim.x * 8) {
        float4 v = *(const float4*)&h[(size_t)r * 128 + cg * 4];
        s0 += v.x; s1 += v.y; s2 += v.z; s3 += v.w;
        q0 += v.x * v.x; q1 += v.y * v.y; q2 += v.z * v.z; q3 += v.w * v.w;
    }
    shs[rl][cg * 4 + 0] = s0; shs[rl][cg * 4 + 1] = s1;
    shs[rl][cg * 4 + 2] = s2; shs[rl][cg * 4 + 3] = s3;
    shq[rl][cg * 4 + 0] = q0; shq[rl][cg * 4 + 1] = q1;
    shq[rl][cg * 4 + 2] = q2; shq[rl][cg * 4 + 3] = q3;
    __syncthreads();
    if (threadIdx.x < 128) {
        float ss = 0, qq = 0;
        #pragma unroll
        for (int r = 0; r < 8; ++r) { ss += shs[r][threadIdx.x]; qq += shq[r][threadIdx.x]; }
        atomicAdd(&stats[threadIdx.x], ss);
        atomicAdd(&stats[128 + threadIdx.x], qq);
    }
}

__global__ void k_bnfinal(const float* __restrict__ stats,
                          const float* __restrict__ gamma, const float* __restrict__ beta,
                          float* __restrict__ bnsc, float* __restrict__ bnsh) {
    int c = threadIdx.x;
    if (c >= 128) return;
    const float invn = 1.0f / (float)NN;
    float m = stats[c] * invn;
    float var = stats[128 + c] * invn - m * m;
    float sc = gamma[c] * rsqrtf(var + EPS_BN);
    bnsc[c] = sc;
    bnsh[c] = beta[c] - m * sc;
}

extern "C" void kernel_launch(void* const* d_in, const int* in_sizes, int n_in,
                              void* d_out, int out_size, void* d_ws, size_t ws_size,
                              hipStream_t stream) {
    const float* x  = (const float*)d_in[0];
    const int*   ei = (const int*)d_in[1];
    const int*   src = ei;        // edge_index[0]
    const int*   dst = ei + NE;   // edge_index[1]
    const float* W0 = (const float*)d_in[2];
    const float* b0 = (const float*)d_in[3];
    const float* W1 = (const float*)d_in[4];
    const float* b1 = (const float*)d_in[5];
    const float* W2 = (const float*)d_in[6];
    const float* b2 = (const float*)d_in[7];
    const float* g0 = (const float*)d_in[8];
    const float* be0 = (const float*)d_in[9];
    const float* g1 = (const float*)d_in[10];
    const float* be1 = (const float*)d_in[11];
    float* out = (float*)d_out;

    // workspace layout (~104 MB)
    float*          A    = (float*)d_ws;                    // N*128 f32
    unsigned short* Hb   = (unsigned short*)(A + (size_t)NN * 128);  // N*128 bf16
    float*          H40  = (float*)Hb;                      // N*40 f32 (aliases Hb; disjoint lifetime)
    float*          ceF  = (float*)(Hb + (size_t)NN * 128); // pad to keep 8B alignment below
    int2*           ce   = (int2*)ceF;                      // NE int2
    float*          dinv = ceF + (size_t)NE * 2;            // N
    float*          stats = dinv + NN;                      // 256
    float*          bnsc = stats + 256;                     // 128
    float*          bnsh = bnsc + 128;                      // 128
    unsigned short* Wt0  = (unsigned short*)(bnsh + 128);   // 128*128 bf16
    unsigned short* Wt1  = Wt0 + 128 * 128;                 // 128*128 bf16
    int*            cnt  = (int*)(Wt1 + 128 * 128);         // N
    int*            fill = cnt + NN;                        // N
    int*            rowptr = fill + NN;                     // N+1
    int*            partial = rowptr + NN + 1;              // 512

    dim3 b256(256);
    int gN = (NN + 255) / 256;
    int gE = (NE + 255) / 256;

    // ---- CSR build + norm ----
    k_zero_int<<<gN, b256, 0, stream>>>(cnt);
    k_hist<<<gE, b256, 0, stream>>>(dst, cnt);
    k_dinv<<<gN, b256, 0, stream>>>(cnt, dinv);
    k_scan1<<<NP, b256, 0, stream>>>(cnt, rowptr, partial);
    k_scan2<<<1, 512, 0, stream>>>(partial);
    k_scan3<<<NP, b256, 0, stream>>>(rowptr, partial, fill);
    k_fill<<<gE, b256, 0, stream>>>(src, dst, dinv, fill, ce);

    // ---- weight prep ----
    k_wconv<<<64, b256, 0, stream>>>(W0, Wt0);
    k_wconv<<<64, b256, 0, stream>>>(W1, Wt1);

    int gG128 = (NN + 3) / 4;

    // ---- layer 0 ----
    k_gemm128_mfma<false><<<NN / 32, b256, 0, stream>>>(x, Wt0, Hb, nullptr, nullptr);
    k_gather128b<<<gG128, b256, 0, stream>>>(Hb, dinv, rowptr, ce, b0, A);
    k_zero_stats<<<1, b256, 0, stream>>>(stats);
    k_bnstats<<<512, b256, 0, stream>>>(A, stats);
    k_bnfinal<<<1, 128, 0, stream>>>(stats, g0, be0, bnsc, bnsh);

    // ---- layer 1 (BN0+relu fused into gemm staging) ----
    k_gemm128_mfma<true><<<NN / 32, b256, 0, stream>>>(A, Wt1, Hb, bnsc, bnsh);
    k_gather128b<<<gG128, b256, 0, stream>>>(Hb, dinv, rowptr, ce, b1, A);
    k_zero_stats<<<1, b256, 0, stream>>>(stats);
    k_bnstats<<<512, b256, 0, stream>>>(A, stats);
    k_bnfinal<<<1, 128, 0, stream>>>(stats, g1, be1, bnsc, bnsh);

    // ---- layer 2 (BN1+relu fused into gemm40 load) ----
    k_gemm40<<<(NN * 40 + 255) / 256, b256, 0, stream>>>(A, W2, H40, bnsc, bnsh);
    k_gather40<<<(NN * 40 + 255) / 256, b256, 0, stream>>>(H40, dinv, rowptr, ce, b2, out);
}

// Round 5
// 489.908 us; speedup vs baseline: 15.4789x; 1.2497x over previous
//
#include <hip/hip_runtime.h>

#define NN 100000
#define NE 1600000
#define EPS_BN 1e-5f
#define NP 391   // ceil(NN/256) scan partials

typedef __attribute__((ext_vector_type(8))) short short8v;
typedef __attribute__((ext_vector_type(4))) float f32x4;

__device__ __forceinline__ unsigned short f2bf(float f) {
    unsigned u = __float_as_uint(f);
    u += 0x7fff + ((u >> 16) & 1);          // RTNE
    return (unsigned short)(u >> 16);
}
__device__ __forceinline__ float bf2f(unsigned short h) {
    return __uint_as_float((unsigned)h << 16);
}

// ---------------- CSR build ----------------
__global__ void k_zero_int(int* __restrict__ cnt) {
    int i = blockIdx.x * 256 + threadIdx.x;
    if (i < NN) cnt[i] = 0;
}

__global__ void k_hist(const int* __restrict__ dst, int* __restrict__ cnt) {
    int e = blockIdx.x * 256 + threadIdx.x;
    if (e < NE) atomicAdd(&cnt[dst[e]], 1);
}

__global__ void k_dinv(const int* __restrict__ cnt, float* __restrict__ dinv) {
    int i = blockIdx.x * 256 + threadIdx.x;
    if (i < NN) dinv[i] = rsqrtf((float)(cnt[i] + 1));   // +1 self-loop
}

__global__ __launch_bounds__(256) void k_scan1(const int* __restrict__ cnt,
                                               int* __restrict__ rowptr,
                                               int* __restrict__ partial) {
    __shared__ int sh[256];
    int i = blockIdx.x * 256 + threadIdx.x;
    int v = (i < NN) ? cnt[i] : 0;
    sh[threadIdx.x] = v;
    __syncthreads();
    for (int off = 1; off < 256; off <<= 1) {
        int t = (threadIdx.x >= off) ? sh[threadIdx.x - off] : 0;
        __syncthreads();
        sh[threadIdx.x] += t;
        __syncthreads();
    }
    if (i < NN) rowptr[i] = sh[threadIdx.x] - v;           // exclusive
    if (threadIdx.x == 255) partial[blockIdx.x] = sh[255]; // block total
}

__global__ __launch_bounds__(512) void k_scan2(int* __restrict__ partial) {
    __shared__ int sh[512];
    int tid = threadIdx.x;
    int v = (tid < NP) ? partial[tid] : 0;
    sh[tid] = v;
    __syncthreads();
    for (int off = 1; off < 512; off <<= 1) {
        int t = (tid >= off) ? sh[tid - off] : 0;
        __syncthreads();
        sh[tid] += t;
        __syncthreads();
    }
    if (tid < NP) partial[tid] = sh[tid] - v;              // exclusive
}

__global__ void k_scan3(int* __restrict__ rowptr, const int* __restrict__ partial,
                        int* __restrict__ fill) {
    int i = blockIdx.x * 256 + threadIdx.x;
    if (i < NN) {
        int v = rowptr[i] + partial[blockIdx.x];
        rowptr[i] = v;
        fill[i] = v;                                       // fill cursor = row start
    }
    if (i == 0) rowptr[NN] = NE;
}

__global__ void k_fill(const int* __restrict__ src, const int* __restrict__ dst,
                       const float* __restrict__ dinv,
                       int* __restrict__ fill, int2* __restrict__ ce) {
    int e = blockIdx.x * 256 + threadIdx.x;
    if (e >= NE) return;
    int s = src[e], d = dst[e];
    int pos = atomicAdd(&fill[d], 1);
    int2 p;
    p.x = s;
    p.y = __float_as_int(dinv[s] * dinv[d]);
    ce[pos] = p;
}

// ---------------- W convert + transpose: Wt[c][k] = bf16(W[k][c]) ----------------
__global__ void k_wconv(const float* __restrict__ W, unsigned short* __restrict__ Wt) {
    int idx = blockIdx.x * 256 + threadIdx.x;
    if (idx >= 128 * 128) return;
    int k = idx >> 7, c = idx & 127;
    Wt[c * 128 + k] = f2bf(W[idx]);
}

// W2: [128][40] -> Wt: [48][128] bf16, cols 40..47 zero
__global__ void k_wconv40(const float* __restrict__ W, unsigned short* __restrict__ Wt) {
    int idx = blockIdx.x * 256 + threadIdx.x;
    if (idx >= 48 * 128) return;
    int c = idx >> 7, k = idx & 127;
    Wt[idx] = (c < 40) ? f2bf(W[k * 40 + c]) : (unsigned short)0;
}

// ---------------- MFMA GEMM: outb[N,128](bf16) = bn(in)[N,128] @ W ----------------
// block = 256 thr (4 waves), 32 rows/block; wave w owns cols w*32..w*32+31
#define XPAD 136   // LDS row stride in ushorts: 272B = 68 words, 68%32=4 -> 2-way max
template <bool BN>
__global__ __launch_bounds__(256) void k_gemm128_mfma(
    const float* __restrict__ in, const unsigned short* __restrict__ Wt,
    unsigned short* __restrict__ outb,
    const float* __restrict__ bnsc, const float* __restrict__ bnsh) {
    __shared__ unsigned short xs[32 * XPAD];
    const int tid = threadIdx.x;
    const int row0 = blockIdx.x * 32;
    for (int i = tid; i < 1024; i += 256) {
        float4 v = ((const float4*)(in + (size_t)row0 * 128))[i];
        int c4 = (i & 31) * 4;
        if (BN) {
            float4 sc = *(const float4*)&bnsc[c4];
            float4 sh = *(const float4*)&bnsh[c4];
            v.x = fmaxf(v.x * sc.x + sh.x, 0.f);
            v.y = fmaxf(v.y * sc.y + sh.y, 0.f);
            v.z = fmaxf(v.z * sc.z + sh.z, 0.f);
            v.w = fmaxf(v.w * sc.w + sh.w, 0.f);
        }
        ushort4 b;
        b.x = f2bf(v.x); b.y = f2bf(v.y); b.z = f2bf(v.z); b.w = f2bf(v.w);
        *(ushort4*)&xs[(i >> 5) * XPAD + c4] = b;
    }
    __syncthreads();

    const int w = tid >> 6;         // wave 0..3
    const int L = tid & 63;
    const int l15 = L & 15;
    const int l4 = L >> 4;          // 0..3
    f32x4 acc[2][2] = {{{0.f, 0.f, 0.f, 0.f}, {0.f, 0.f, 0.f, 0.f}},
                       {{0.f, 0.f, 0.f, 0.f}, {0.f, 0.f, 0.f, 0.f}}};
    const unsigned short* Wb0 = Wt + (size_t)(w * 32 + l15) * 128;
    const unsigned short* Wb1 = Wt + (size_t)(w * 32 + 16 + l15) * 128;
    #pragma unroll
    for (int kk = 0; kk < 4; ++kk) {
        int k0 = kk * 32 + l4 * 8;
        short8v a0 = *(const short8v*)&xs[l15 * XPAD + k0];
        short8v a1 = *(const short8v*)&xs[(16 + l15) * XPAD + k0];
        short8v b0 = *(const short8v*)&Wb0[k0];
        short8v b1 = *(const short8v*)&Wb1[k0];
        acc[0][0] = __builtin_amdgcn_mfma_f32_16x16x32_bf16(a0, b0, acc[0][0], 0, 0, 0);
        acc[0][1] = __builtin_amdgcn_mfma_f32_16x16x32_bf16(a0, b1, acc[0][1], 0, 0, 0);
        acc[1][0] = __builtin_amdgcn_mfma_f32_16x16x32_bf16(a1, b0, acc[1][0], 0, 0, 0);
        acc[1][1] = __builtin_amdgcn_mfma_f32_16x16x32_bf16(a1, b1, acc[1][1], 0, 0, 0);
    }
    // C/D layout: col = lane&15, row = (lane>>4)*4 + reg
    #pragma unroll
    for (int h = 0; h < 2; ++h)
        #pragma unroll
        for (int c = 0; c < 2; ++c) {
            int colg = w * 32 + c * 16 + l15;
            #pragma unroll
            for (int r = 0; r < 4; ++r) {
                int rowg = row0 + h * 16 + l4 * 4 + r;
                outb[(size_t)rowg * 128 + colg] = f2bf(acc[h][c][r]);
            }
        }
}

// ---------------- MFMA GEMM: out[N,40](f32) = bn(in)[N,128] @ W2 ----------------
// block = 256 thr (4 waves), 64 rows; wave w owns rows w*16..w*16+15, all 48 cols
__global__ __launch_bounds__(256) void k_gemm40_mfma(
    const float* __restrict__ in, const unsigned short* __restrict__ Wt,
    float* __restrict__ out,
    const float* __restrict__ bnsc, const float* __restrict__ bnsh) {
    __shared__ unsigned short xs[64 * XPAD];
    const int tid = threadIdx.x;
    const int row0 = blockIdx.x * 64;
    for (int i = tid; i < 2048; i += 256) {
        int r = i >> 5;
        int c4 = (i & 31) * 4;
        float4 v = {0.f, 0.f, 0.f, 0.f};
        if (row0 + r < NN) v = *(const float4*)(in + (size_t)(row0 + r) * 128 + c4);
        float4 sc = *(const float4*)&bnsc[c4];
        float4 sh = *(const float4*)&bnsh[c4];
        v.x = fmaxf(v.x * sc.x + sh.x, 0.f);
        v.y = fmaxf(v.y * sc.y + sh.y, 0.f);
        v.z = fmaxf(v.z * sc.z + sh.z, 0.f);
        v.w = fmaxf(v.w * sc.w + sh.w, 0.f);
        ushort4 b;
        b.x = f2bf(v.x); b.y = f2bf(v.y); b.z = f2bf(v.z); b.w = f2bf(v.w);
        *(ushort4*)&xs[r * XPAD + c4] = b;
    }
    __syncthreads();

    const int w = tid >> 6;
    const int L = tid & 63;
    const int l15 = L & 15;
    const int l4 = L >> 4;
    f32x4 acc[3] = {{0.f, 0.f, 0.f, 0.f}, {0.f, 0.f, 0.f, 0.f}, {0.f, 0.f, 0.f, 0.f}};
    #pragma unroll
    for (int kk = 0; kk < 4; ++kk) {
        int k0 = kk * 32 + l4 * 8;
        short8v a = *(const short8v*)&xs[(w * 16 + l15) * XPAD + k0];
        #pragma unroll
        for (int cgi = 0; cgi < 3; ++cgi) {
            short8v b = *(const short8v*)&Wt[(size_t)(cgi * 16 + l15) * 128 + k0];
            acc[cgi] = __builtin_amdgcn_mfma_f32_16x16x32_bf16(a, b, acc[cgi], 0, 0, 0);
        }
    }
    #pragma unroll
    for (int cgi = 0; cgi < 3; ++cgi) {
        int colg = cgi * 16 + l15;
        if (colg < 40) {
            #pragma unroll
            for (int r = 0; r < 4; ++r) {
                int rowg = row0 + w * 16 + l4 * 4 + r;
                if (rowg < NN) out[(size_t)rowg * 40 + colg] = acc[cgi][r];
            }
        }
    }
}

// ---------------- CSR gather (bf16 h rows, 256B each), F=128 ----------------
__global__ __launch_bounds__(256) void k_gather128b(
    const unsigned short* __restrict__ hb, const float* __restrict__ dinv,
    const int* __restrict__ rowptr, const int2* __restrict__ ce,
    const float* __restrict__ bias, float* __restrict__ agg) {
    int node = blockIdx.x * 4 + (threadIdx.x >> 6);
    if (node >= NN) return;
    int lane = threadIdx.x & 63;
    int c = lane * 2;
    float d = dinv[node];
    float s = d * d;
    ushort2 hv = *(const ushort2*)(hb + (size_t)node * 128 + c);
    float2 acc;
    acc.x = bf2f(hv.x) * s + bias[c];
    acc.y = bf2f(hv.y) * s + bias[c + 1];
    int e = rowptr[node], e1 = rowptr[node + 1];
    for (; e + 4 <= e1; e += 4) {
        int2 p0 = ce[e], p1 = ce[e + 1], p2 = ce[e + 2], p3 = ce[e + 3];
        ushort2 v0 = *(const ushort2*)(hb + (size_t)p0.x * 128 + c);
        ushort2 v1 = *(const ushort2*)(hb + (size_t)p1.x * 128 + c);
        ushort2 v2 = *(const ushort2*)(hb + (size_t)p2.x * 128 + c);
        ushort2 v3 = *(const ushort2*)(hb + (size_t)p3.x * 128 + c);
        float w0 = __int_as_float(p0.y), w1 = __int_as_float(p1.y);
        float w2 = __int_as_float(p2.y), w3 = __int_as_float(p3.y);
        acc.x += bf2f(v0.x) * w0; acc.y += bf2f(v0.y) * w0;
        acc.x += bf2f(v1.x) * w1; acc.y += bf2f(v1.y) * w1;
        acc.x += bf2f(v2.x) * w2; acc.y += bf2f(v2.y) * w2;
        acc.x += bf2f(v3.x) * w3; acc.y += bf2f(v3.y) * w3;
    }
    for (; e < e1; ++e) {
        int2 p = ce[e];
        ushort2 v = *(const ushort2*)(hb + (size_t)p.x * 128 + c);
        float w = __int_as_float(p.y);
        acc.x += bf2f(v.x) * w; acc.y += bf2f(v.y) * w;
    }
    *(float2*)(agg + (size_t)node * 128 + c) = acc;
}

// ---------------- CSR gather, F=40 (fp32) ----------------
__global__ void k_gather40(
    const float* __restrict__ h, const float* __restrict__ dinv,
    const int* __restrict__ rowptr, const int2* __restrict__ ce,
    const float* __restrict__ bias, float* __restrict__ out) {
    int idx = blockIdx.x * 256 + threadIdx.x;
    if (idx >= NN * 40) return;
    int node = idx / 40, c = idx - node * 40;
    float d = dinv[node];
    float acc = h[(size_t)node * 40 + c] * d * d + bias[c];
    int e = rowptr[node], e1 = rowptr[node + 1];
    for (; e + 2 <= e1; e += 2) {
        int2 p0 = ce[e], p1 = ce[e + 1];
        float v0 = h[(size_t)p0.x * 40 + c];
        float v1 = h[(size_t)p1.x * 40 + c];
        acc += v0 * __int_as_float(p0.y) + v1 * __int_as_float(p1.y);
    }
    for (; e < e1; ++e) {
        int2 p = ce[e];
        acc += h[(size_t)p.x * 40 + c] * __int_as_float(p.y);
    }
    out[idx] = acc;
}

// ---------------- batchnorm stats ----------------
__global__ void k_zero_stats(float* __restrict__ stats) {
    stats[threadIdx.x] = 0.f;   // 256: [0:128) sum, [128:256) sumsq
}

__global__ __launch_bounds__(256) void k_bnstats(const float* __restrict__ h,
                                                 float* __restrict__ stats) {
    __shared__ float shs[8][132];
    __shared__ float shq[8][132];
    int cg = threadIdx.x & 31;
    int rl = threadIdx.x >> 5;
    float s0 = 0, s1 = 0, s2 = 0, s3 = 0;
    float q0 = 0, q1 = 0, q2 = 0, q3 = 0;
    for (int r = blockIdx.x * 8 + rl; r < NN; r += gridDim.x * 8) {
        float4 v = *(const float4*)&h[(size_t)r * 128 + cg * 4];
        s0 += v.x; s1 += v.y; s2 += v.z; s3 += v.w;
        q0 += v.x * v.x; q1 += v.y * v.y; q2 += v.z * v.z; q3 += v.w * v.w;
    }
    shs[rl][cg * 4 + 0] = s0; shs[rl][cg * 4 + 1] = s1;
    shs[rl][cg * 4 + 2] = s2; shs[rl][cg * 4 + 3] = s3;
    shq[rl][cg * 4 + 0] = q0; shq[rl][cg * 4 + 1] = q1;
    shq[rl][cg * 4 + 2] = q2; shq[rl][cg * 4 + 3] = q3;
    __syncthreads();
    if (threadIdx.x < 128) {
        float ss = 0, qq = 0;
        #pragma unroll
        for (int r = 0; r < 8; ++r) { ss += shs[r][threadIdx.x]; qq += shq[r][threadIdx.x]; }
        atomicAdd(&stats[threadIdx.x], ss);
        atomicAdd(&stats[128 + threadIdx.x], qq);
    }
}

__global__ void k_bnfinal(const float* __restrict__ stats,
                          const float* __restrict__ gamma, const float* __restrict__ beta,
                          float* __restrict__ bnsc, float* __restrict__ bnsh) {
    int c = threadIdx.x;
    if (c >= 128) return;
    const float invn = 1.0f / (float)NN;
    float m = stats[c] * invn;
    float var = stats[128 + c] * invn - m * m;
    float sc = gamma[c] * rsqrtf(var + EPS_BN);
    bnsc[c] = sc;
    bnsh[c] = beta[c] - m * sc;
}

extern "C" void kernel_launch(void* const* d_in, const int* in_sizes, int n_in,
                              void* d_out, int out_size, void* d_ws, size_t ws_size,
                              hipStream_t stream) {
    const float* x  = (const float*)d_in[0];
    const int*   ei = (const int*)d_in[1];
    const int*   src = ei;        // edge_index[0]
    const int*   dst = ei + NE;   // edge_index[1]
    const float* W0 = (const float*)d_in[2];
    const float* b0 = (const float*)d_in[3];
    const float* W1 = (const float*)d_in[4];
    const float* b1 = (const float*)d_in[5];
    const float* W2 = (const float*)d_in[6];
    const float* b2 = (const float*)d_in[7];
    const float* g0 = (const float*)d_in[8];
    const float* be0 = (const float*)d_in[9];
    const float* g1 = (const float*)d_in[10];
    const float* be1 = (const float*)d_in[11];
    float* out = (float*)d_out;

    // workspace layout (~104 MB)
    float*          A    = (float*)d_ws;                    // N*128 f32
    unsigned short* Hb   = (unsigned short*)(A + (size_t)NN * 128);  // N*128 bf16
    float*          H40  = (float*)Hb;                      // N*40 f32 (aliases Hb; disjoint lifetime)
    float*          ceF  = (float*)(Hb + (size_t)NN * 128);
    int2*           ce   = (int2*)ceF;                      // NE int2
    float*          dinv = ceF + (size_t)NE * 2;            // N
    float*          stats = dinv + NN;                      // 256
    float*          bnsc = stats + 256;                     // 128
    float*          bnsh = bnsc + 128;                      // 128
    unsigned short* Wt0  = (unsigned short*)(bnsh + 128);   // 128*128 bf16
    unsigned short* Wt1  = Wt0 + 128 * 128;                 // 128*128 bf16
    unsigned short* Wt2  = Wt1 + 128 * 128;                 // 48*128 bf16
    int*            cnt  = (int*)(Wt2 + 48 * 128);          // N
    int*            fill = cnt + NN;                        // N
    int*            rowptr = fill + NN;                     // N+1
    int*            partial = rowptr + NN + 1;              // 512

    dim3 b256(256);
    int gN = (NN + 255) / 256;
    int gE = (NE + 255) / 256;

    // ---- CSR build + norm ----
    k_zero_int<<<gN, b256, 0, stream>>>(cnt);
    k_hist<<<gE, b256, 0, stream>>>(dst, cnt);
    k_dinv<<<gN, b256, 0, stream>>>(cnt, dinv);
    k_scan1<<<NP, b256, 0, stream>>>(cnt, rowptr, partial);
    k_scan2<<<1, 512, 0, stream>>>(partial);
    k_scan3<<<NP, b256, 0, stream>>>(rowptr, partial, fill);
    k_fill<<<gE, b256, 0, stream>>>(src, dst, dinv, fill, ce);

    // ---- weight prep ----
    k_wconv<<<64, b256, 0, stream>>>(W0, Wt0);
    k_wconv<<<64, b256, 0, stream>>>(W1, Wt1);
    k_wconv40<<<24, b256, 0, stream>>>(W2, Wt2);

    int gG128 = (NN + 3) / 4;

    // ---- layer 0 ----
    k_gemm128_mfma<false><<<NN / 32, b256, 0, stream>>>(x, Wt0, Hb, nullptr, nullptr);
    k_gather128b<<<gG128, b256, 0, stream>>>(Hb, dinv, rowptr, ce, b0, A);
    k_zero_stats<<<1, b256, 0, stream>>>(stats);
    k_bnstats<<<512, b256, 0, stream>>>(A, stats);
    k_bnfinal<<<1, 128, 0, stream>>>(stats, g0, be0, bnsc, bnsh);

    // ---- layer 1 (BN0+relu fused into gemm staging) ----
    k_gemm128_mfma<true><<<NN / 32, b256, 0, stream>>>(A, Wt1, Hb, bnsc, bnsh);
    k_gather128b<<<gG128, b256, 0, stream>>>(Hb, dinv, rowptr, ce, b1, A);
    k_zero_stats<<<1, b256, 0, stream>>>(stats);
    k_bnstats<<<512, b256, 0, stream>>>(A, stats);
    k_bnfinal<<<1, 128, 0, stream>>>(stats, g1, be1, bnsc, bnsh);

    // ---- layer 2 (BN1+relu fused into MFMA gemm40 staging) ----
    k_gemm40_mfma<<<(NN + 63) / 64, b256, 0, stream>>>(A, Wt2, H40, bnsc, bnsh);
    k_gather40<<<(NN * 40 + 255) / 256, b256, 0, stream>>>(H40, dinv, rowptr, ce, b2, out);
}

// Round 6
// 468.174 us; speedup vs baseline: 16.1975x; 1.0464x over previous
//
#include <hip/hip_runtime.h>

#define NN 100000
#define NE 1600000
#define EPS_BN 1e-5f
#define NP 391     // ceil(NN/256) scan partials
#define BUCKW 12500  // NN / 8 buckets (one per XCD)

typedef __attribute__((ext_vector_type(8))) short short8v;
typedef __attribute__((ext_vector_type(4))) float f32x4;

__device__ __forceinline__ unsigned short f2bf(float f) {
    unsigned u = __float_as_uint(f);
    u += 0x7fff + ((u >> 16) & 1);          // RTNE
    return (unsigned short)(u >> 16);
}
__device__ __forceinline__ float bf2f(unsigned short h) {
    return __uint_as_float((unsigned)h << 16);
}

// ---------------- CSR build ----------------
__global__ void k_zero_int(int* __restrict__ cnt) {
    int i = blockIdx.x * 256 + threadIdx.x;
    if (i < NN) cnt[i] = 0;
}

// XCD-bucketed histogram: block b -> edge chunk (b>>3), bucket (b&7).
// With round-robin block->XCD dispatch, bucket b&7 stays on one XCD -> L2-local atomics.
__global__ void k_hist8(const int* __restrict__ dst, int* __restrict__ cnt) {
    int xcd = blockIdx.x & 7;
    int e = (blockIdx.x >> 3) * 256 + threadIdx.x;
    if (e >= NE) return;
    int d = dst[e];
    if (d / BUCKW == xcd) atomicAdd(&cnt[d], 1);
}

__global__ void k_dinv(const int* __restrict__ cnt, float* __restrict__ dinv) {
    int i = blockIdx.x * 256 + threadIdx.x;
    if (i < NN) dinv[i] = rsqrtf((float)(cnt[i] + 1));   // +1 self-loop
}

__global__ __launch_bounds__(256) void k_scan1(const int* __restrict__ cnt,
                                               int* __restrict__ rowptr,
                                               int* __restrict__ partial) {
    __shared__ int sh[256];
    int i = blockIdx.x * 256 + threadIdx.x;
    int v = (i < NN) ? cnt[i] : 0;
    sh[threadIdx.x] = v;
    __syncthreads();
    for (int off = 1; off < 256; off <<= 1) {
        int t = (threadIdx.x >= off) ? sh[threadIdx.x - off] : 0;
        __syncthreads();
        sh[threadIdx.x] += t;
        __syncthreads();
    }
    if (i < NN) rowptr[i] = sh[threadIdx.x] - v;           // exclusive
    if (threadIdx.x == 255) partial[blockIdx.x] = sh[255]; // block total
}

__global__ __launch_bounds__(512) void k_scan2(int* __restrict__ partial) {
    __shared__ int sh[512];
    int tid = threadIdx.x;
    int v = (tid < NP) ? partial[tid] : 0;
    sh[tid] = v;
    __syncthreads();
    for (int off = 1; off < 512; off <<= 1) {
        int t = (tid >= off) ? sh[tid - off] : 0;
        __syncthreads();
        sh[tid] += t;
        __syncthreads();
    }
    if (tid < NP) partial[tid] = sh[tid] - v;              // exclusive
}

__global__ void k_scan3(int* __restrict__ rowptr, const int* __restrict__ partial,
                        int* __restrict__ fill) {
    int i = blockIdx.x * 256 + threadIdx.x;
    if (i < NN) {
        int v = rowptr[i] + partial[blockIdx.x];
        rowptr[i] = v;
        fill[i] = v;                                       // fill cursor = row start
    }
    if (i == 0) rowptr[NN] = NE;
}

// XCD-bucketed fill: ce lines + fill cursors for a bucket stay on one XCD.
__global__ void k_fill8(const int* __restrict__ src, const int* __restrict__ dst,
                        const float* __restrict__ dinv,
                        int* __restrict__ fill, int2* __restrict__ ce) {
    int xcd = blockIdx.x & 7;
    int e = (blockIdx.x >> 3) * 256 + threadIdx.x;
    if (e >= NE) return;
    int d = dst[e];
    if (d / BUCKW != xcd) return;
    int s = src[e];
    int pos = atomicAdd(&fill[d], 1);
    int2 p;
    p.x = s;
    p.y = __float_as_int(dinv[s] * dinv[d]);
    ce[pos] = p;
}

// ---------------- W convert + transpose: Wt[c][k] = bf16(W[k][c]) ----------------
__global__ void k_wconv(const float* __restrict__ W, unsigned short* __restrict__ Wt) {
    int idx = blockIdx.x * 256 + threadIdx.x;
    if (idx >= 128 * 128) return;
    int k = idx >> 7, c = idx & 127;
    Wt[c * 128 + k] = f2bf(W[idx]);
}

// W2: [128][40] -> Wt: [48][128] bf16, cols 40..47 zero
__global__ void k_wconv40(const float* __restrict__ W, unsigned short* __restrict__ Wt) {
    int idx = blockIdx.x * 256 + threadIdx.x;
    if (idx >= 48 * 128) return;
    int c = idx >> 7, k = idx & 127;
    Wt[idx] = (c < 40) ? f2bf(W[k * 40 + c]) : (unsigned short)0;
}

// ---------------- MFMA GEMM: outb[N,128](bf16) = bn(in)[N,128] @ W ----------------
#define XPAD 136   // LDS row stride in ushorts: 272B = 68 words, 68%32=4 -> 2-way max
template <bool BN>
__global__ __launch_bounds__(256) void k_gemm128_mfma(
    const float* __restrict__ in, const unsigned short* __restrict__ Wt,
    unsigned short* __restrict__ outb,
    const float* __restrict__ bnsc, const float* __restrict__ bnsh) {
    __shared__ unsigned short xs[32 * XPAD];
    const int tid = threadIdx.x;
    const int row0 = blockIdx.x * 32;
    for (int i = tid; i < 1024; i += 256) {
        float4 v = ((const float4*)(in + (size_t)row0 * 128))[i];
        int c4 = (i & 31) * 4;
        if (BN) {
            float4 sc = *(const float4*)&bnsc[c4];
            float4 sh = *(const float4*)&bnsh[c4];
            v.x = fmaxf(v.x * sc.x + sh.x, 0.f);
            v.y = fmaxf(v.y * sc.y + sh.y, 0.f);
            v.z = fmaxf(v.z * sc.z + sh.z, 0.f);
            v.w = fmaxf(v.w * sc.w + sh.w, 0.f);
        }
        ushort4 b;
        b.x = f2bf(v.x); b.y = f2bf(v.y); b.z = f2bf(v.z); b.w = f2bf(v.w);
        *(ushort4*)&xs[(i >> 5) * XPAD + c4] = b;
    }
    __syncthreads();

    const int w = tid >> 6;         // wave 0..3
    const int L = tid & 63;
    const int l15 = L & 15;
    const int l4 = L >> 4;          // 0..3
    f32x4 acc[2][2] = {{{0.f, 0.f, 0.f, 0.f}, {0.f, 0.f, 0.f, 0.f}},
                       {{0.f, 0.f, 0.f, 0.f}, {0.f, 0.f, 0.f, 0.f}}};
    const unsigned short* Wb0 = Wt + (size_t)(w * 32 + l15) * 128;
    const unsigned short* Wb1 = Wt + (size_t)(w * 32 + 16 + l15) * 128;
    #pragma unroll
    for (int kk = 0; kk < 4; ++kk) {
        int k0 = kk * 32 + l4 * 8;
        short8v a0 = *(const short8v*)&xs[l15 * XPAD + k0];
        short8v a1 = *(const short8v*)&xs[(16 + l15) * XPAD + k0];
        short8v b0 = *(const short8v*)&Wb0[k0];
        short8v b1 = *(const short8v*)&Wb1[k0];
        acc[0][0] = __builtin_amdgcn_mfma_f32_16x16x32_bf16(a0, b0, acc[0][0], 0, 0, 0);
        acc[0][1] = __builtin_amdgcn_mfma_f32_16x16x32_bf16(a0, b1, acc[0][1], 0, 0, 0);
        acc[1][0] = __builtin_amdgcn_mfma_f32_16x16x32_bf16(a1, b0, acc[1][0], 0, 0, 0);
        acc[1][1] = __builtin_amdgcn_mfma_f32_16x16x32_bf16(a1, b1, acc[1][1], 0, 0, 0);
    }
    // C/D layout: col = lane&15, row = (lane>>4)*4 + reg
    #pragma unroll
    for (int h = 0; h < 2; ++h)
        #pragma unroll
        for (int c = 0; c < 2; ++c) {
            int colg = w * 32 + c * 16 + l15;
            #pragma unroll
            for (int r = 0; r < 4; ++r) {
                int rowg = row0 + h * 16 + l4 * 4 + r;
                outb[(size_t)rowg * 128 + colg] = f2bf(acc[h][c][r]);
            }
        }
}

// ---------------- MFMA GEMM: out[N,40](bf16) = bn(in)[N,128] @ W2 ----------------
__global__ __launch_bounds__(256) void k_gemm40_mfma(
    const float* __restrict__ in, const unsigned short* __restrict__ Wt,
    unsigned short* __restrict__ outb,
    const float* __restrict__ bnsc, const float* __restrict__ bnsh) {
    __shared__ unsigned short xs[64 * XPAD];
    const int tid = threadIdx.x;
    const int row0 = blockIdx.x * 64;
    for (int i = tid; i < 2048; i += 256) {
        int r = i >> 5;
        int c4 = (i & 31) * 4;
        float4 v = {0.f, 0.f, 0.f, 0.f};
        if (row0 + r < NN) v = *(const float4*)(in + (size_t)(row0 + r) * 128 + c4);
        float4 sc = *(const float4*)&bnsc[c4];
        float4 sh = *(const float4*)&bnsh[c4];
        v.x = fmaxf(v.x * sc.x + sh.x, 0.f);
        v.y = fmaxf(v.y * sc.y + sh.y, 0.f);
        v.z = fmaxf(v.z * sc.z + sh.z, 0.f);
        v.w = fmaxf(v.w * sc.w + sh.w, 0.f);
        ushort4 b;
        b.x = f2bf(v.x); b.y = f2bf(v.y); b.z = f2bf(v.z); b.w = f2bf(v.w);
        *(ushort4*)&xs[r * XPAD + c4] = b;
    }
    __syncthreads();

    const int w = tid >> 6;
    const int L = tid & 63;
    const int l15 = L & 15;
    const int l4 = L >> 4;
    f32x4 acc[3] = {{0.f, 0.f, 0.f, 0.f}, {0.f, 0.f, 0.f, 0.f}, {0.f, 0.f, 0.f, 0.f}};
    #pragma unroll
    for (int kk = 0; kk < 4; ++kk) {
        int k0 = kk * 32 + l4 * 8;
        short8v a = *(const short8v*)&xs[(w * 16 + l15) * XPAD + k0];
        #pragma unroll
        for (int cgi = 0; cgi < 3; ++cgi) {
            short8v b = *(const short8v*)&Wt[(size_t)(cgi * 16 + l15) * 128 + k0];
            acc[cgi] = __builtin_amdgcn_mfma_f32_16x16x32_bf16(a, b, acc[cgi], 0, 0, 0);
        }
    }
    #pragma unroll
    for (int cgi = 0; cgi < 3; ++cgi) {
        int colg = cgi * 16 + l15;
        if (colg < 40) {
            #pragma unroll
            for (int r = 0; r < 4; ++r) {
                int rowg = row0 + w * 16 + l4 * 4 + r;
                if (rowg < NN) outb[(size_t)rowg * 40 + colg] = f2bf(acc[cgi][r]);
            }
        }
    }
}

// ---------------- CSR gather (bf16 h rows, 256B each) + fused BN partial stats ----
__global__ void k_zero_stats2(float* __restrict__ stats2) {
    stats2[blockIdx.x * 256 + threadIdx.x] = 0.f;   // 64 copies x 256
}

__global__ __launch_bounds__(256) void k_gather128b(
    const unsigned short* __restrict__ hb, const float* __restrict__ dinv,
    const int* __restrict__ rowptr, const int2* __restrict__ ce,
    const float* __restrict__ bias, float* __restrict__ agg,
    float* __restrict__ stats2) {
    __shared__ float comb[4][256];
    const int w = threadIdx.x >> 6;
    const int lane = threadIdx.x & 63;
    const int node = blockIdx.x * 4 + w;
    const int c = lane * 2;
    float2 acc = {0.f, 0.f};
    if (node < NN) {
        float d = dinv[node];
        float s = d * d;
        ushort2 hv = *(const ushort2*)(hb + (size_t)node * 128 + c);
        acc.x = bf2f(hv.x) * s + bias[c];
        acc.y = bf2f(hv.y) * s + bias[c + 1];
        int e = rowptr[node], e1 = rowptr[node + 1];
        for (; e + 4 <= e1; e += 4) {
            int2 p0 = ce[e], p1 = ce[e + 1], p2 = ce[e + 2], p3 = ce[e + 3];
            ushort2 v0 = *(const ushort2*)(hb + (size_t)p0.x * 128 + c);
            ushort2 v1 = *(const ushort2*)(hb + (size_t)p1.x * 128 + c);
            ushort2 v2 = *(const ushort2*)(hb + (size_t)p2.x * 128 + c);
            ushort2 v3 = *(const ushort2*)(hb + (size_t)p3.x * 128 + c);
            float w0 = __int_as_float(p0.y), w1 = __int_as_float(p1.y);
            float w2 = __int_as_float(p2.y), w3 = __int_as_float(p3.y);
            acc.x += bf2f(v0.x) * w0; acc.y += bf2f(v0.y) * w0;
            acc.x += bf2f(v1.x) * w1; acc.y += bf2f(v1.y) * w1;
            acc.x += bf2f(v2.x) * w2; acc.y += bf2f(v2.y) * w2;
            acc.x += bf2f(v3.x) * w3; acc.y += bf2f(v3.y) * w3;
        }
        for (; e < e1; ++e) {
            int2 p = ce[e];
            ushort2 v = *(const ushort2*)(hb + (size_t)p.x * 128 + c);
            float wt = __int_as_float(p.y);
            acc.x += bf2f(v.x) * wt; acc.y += bf2f(v.y) * wt;
        }
        *(float2*)(agg + (size_t)node * 128 + c) = acc;
    }
    // fused BN partial stats: block-level reduce then 1 atomic per slot
    comb[w][c] = acc.x;
    comb[w][c + 1] = acc.y;
    comb[w][128 + c] = acc.x * acc.x;
    comb[w][129 + c] = acc.y * acc.y;
    __syncthreads();
    int t = threadIdx.x;
    float v = comb[0][t] + comb[1][t] + comb[2][t] + comb[3][t];
    atomicAdd(&stats2[(blockIdx.x & 63) * 256 + t], v);
}

// ---------------- CSR gather, F=40 (bf16 h) ----------------
__global__ void k_gather40(
    const unsigned short* __restrict__ hb, const float* __restrict__ dinv,
    const int* __restrict__ rowptr, const int2* __restrict__ ce,
    const float* __restrict__ bias, float* __restrict__ out) {
    int idx = blockIdx.x * 256 + threadIdx.x;
    if (idx >= NN * 40) return;
    int node = idx / 40, c = idx - node * 40;
    float d = dinv[node];
    float acc = bf2f(hb[(size_t)node * 40 + c]) * d * d + bias[c];
    int e = rowptr[node], e1 = rowptr[node + 1];
    for (; e + 2 <= e1; e += 2) {
        int2 p0 = ce[e], p1 = ce[e + 1];
        float v0 = bf2f(hb[(size_t)p0.x * 40 + c]);
        float v1 = bf2f(hb[(size_t)p1.x * 40 + c]);
        acc += v0 * __int_as_float(p0.y) + v1 * __int_as_float(p1.y);
    }
    for (; e < e1; ++e) {
        int2 p = ce[e];
        acc += bf2f(hb[(size_t)p.x * 40 + c]) * __int_as_float(p.y);
    }
    out[idx] = acc;
}

// fold 64 stat copies + gamma/beta into per-column scale/shift
__global__ void k_bnfinal2(const float* __restrict__ stats2,
                           const float* __restrict__ gamma, const float* __restrict__ beta,
                           float* __restrict__ bnsc, float* __restrict__ bnsh) {
    int c = threadIdx.x;
    if (c >= 128) return;
    float s = 0.f, q = 0.f;
    for (int k = 0; k < 64; ++k) {
        s += stats2[k * 256 + c];
        q += stats2[k * 256 + 128 + c];
    }
    const float invn = 1.0f / (float)NN;
    float m = s * invn;
    float var = q * invn - m * m;
    float sc = gamma[c] * rsqrtf(var + EPS_BN);
    bnsc[c] = sc;
    bnsh[c] = beta[c] - m * sc;
}

extern "C" void kernel_launch(void* const* d_in, const int* in_sizes, int n_in,
                              void* d_out, int out_size, void* d_ws, size_t ws_size,
                              hipStream_t stream) {
    const float* x  = (const float*)d_in[0];
    const int*   ei = (const int*)d_in[1];
    const int*   src = ei;        // edge_index[0]
    const int*   dst = ei + NE;   // edge_index[1]
    const float* W0 = (const float*)d_in[2];
    const float* b0 = (const float*)d_in[3];
    const float* W1 = (const float*)d_in[4];
    const float* b1 = (const float*)d_in[5];
    const float* W2 = (const float*)d_in[6];
    const float* b2 = (const float*)d_in[7];
    const float* g0 = (const float*)d_in[8];
    const float* be0 = (const float*)d_in[9];
    const float* g1 = (const float*)d_in[10];
    const float* be1 = (const float*)d_in[11];
    float* out = (float*)d_out;

    // workspace layout (~92 MB)
    float*          A    = (float*)d_ws;                    // N*128 f32
    unsigned short* Hb   = (unsigned short*)(A + (size_t)NN * 128);  // N*128 bf16
    unsigned short* H40  = Hb;                              // N*40 bf16 (aliases Hb; disjoint lifetime)
    float*          ceF  = (float*)(Hb + (size_t)NN * 128);
    int2*           ce   = (int2*)ceF;                      // NE int2
    float*          dinv = ceF + (size_t)NE * 2;            // N
    float*          stats2 = dinv + NN;                     // 64*256
    float*          bnsc = stats2 + 64 * 256;               // 128
    float*          bnsh = bnsc + 128;                      // 128
    unsigned short* Wt0  = (unsigned short*)(bnsh + 128);   // 128*128 bf16
    unsigned short* Wt1  = Wt0 + 128 * 128;                 // 128*128 bf16
    unsigned short* Wt2  = Wt1 + 128 * 128;                 // 48*128 bf16
    int*            cnt  = (int*)(Wt2 + 48 * 128);          // N
    int*            fill = cnt + NN;                        // N
    int*            rowptr = fill + NN;                     // N+1
    int*            partial = rowptr + NN + 1;              // 512

    dim3 b256(256);
    int gN = (NN + 255) / 256;
    int gE = (NE + 255) / 256;

    // ---- CSR build + norm (XCD-bucketed hist/fill) ----
    k_zero_int<<<gN, b256, 0, stream>>>(cnt);
    k_hist8<<<gE * 8, b256, 0, stream>>>(dst, cnt);
    k_dinv<<<gN, b256, 0, stream>>>(cnt, dinv);
    k_scan1<<<NP, b256, 0, stream>>>(cnt, rowptr, partial);
    k_scan2<<<1, 512, 0, stream>>>(partial);
    k_scan3<<<NP, b256, 0, stream>>>(rowptr, partial, fill);
    k_fill8<<<gE * 8, b256, 0, stream>>>(src, dst, dinv, fill, ce);

    // ---- weight prep ----
    k_wconv<<<64, b256, 0, stream>>>(W0, Wt0);
    k_wconv<<<64, b256, 0, stream>>>(W1, Wt1);
    k_wconv40<<<24, b256, 0, stream>>>(W2, Wt2);

    int gG128 = (NN + 3) / 4;

    // ---- layer 0 ----
    k_gemm128_mfma<false><<<NN / 32, b256, 0, stream>>>(x, Wt0, Hb, nullptr, nullptr);
    k_zero_stats2<<<64, b256, 0, stream>>>(stats2);
    k_gather128b<<<gG128, b256, 0, stream>>>(Hb, dinv, rowptr, ce, b0, A, stats2);
    k_bnfinal2<<<1, 128, 0, stream>>>(stats2, g0, be0, bnsc, bnsh);

    // ---- layer 1 (BN0+relu fused into gemm staging) ----
    k_gemm128_mfma<true><<<NN / 32, b256, 0, stream>>>(A, Wt1, Hb, bnsc, bnsh);
    k_zero_stats2<<<64, b256, 0, stream>>>(stats2);
    k_gather128b<<<gG128, b256, 0, stream>>>(Hb, dinv, rowptr, ce, b1, A, stats2);
    k_bnfinal2<<<1, 128, 0, stream>>>(stats2, g1, be1, bnsc, bnsh);

    // ---- layer 2 (BN1+relu fused into MFMA gemm40 staging; bf16 H40) ----
    k_gemm40_mfma<<<(NN + 63) / 64, b256, 0, stream>>>(A, Wt2, H40, bnsc, bnsh);
    k_gather40<<<(NN * 40 + 255) / 256, b256, 0, stream>>>(H40, dinv, rowptr, ce, b2, out);
}